// Round 2
// baseline (813.814 us; speedup 1.0000x reference)
//
#include <hip/hip_runtime.h>

#define TT   2000
#define NG   4000
#define WARM 365
#define LENF 15
#define NPHY 12
#define NMULT 4

// One thread per (g, m) chain: 16000 threads, lanes interleaved so the 4
// multipliers of one grid cell occupy one quad (shfl_xor 1,2 = mean over m).
__global__ __launch_bounds__(64, 1) void hbv_route_kernel(
    const float* __restrict__ xphy,   // [T, G, 3] (p, t, pet)
    const float* __restrict__ prm,    // [1, G, 50]
    float* __restrict__ out)          // [T-WARM, G]
{
    const int tid = blockIdx.x * 64 + threadIdx.x;
    const int g = tid >> 2;
    const int m = tid & 3;
    if (g >= NG) return;

    const float* pg = prm + (size_t)g * (NPHY * NMULT + 2);

    const float lb[NPHY] = {1.0f, 50.0f, 0.05f, 0.01f, 0.001f, 0.2f, 0.0f, 0.0f, -2.5f, 0.5f, 0.0f, 0.0f};
    const float ub[NPHY] = {6.0f, 1000.0f, 0.9f, 0.5f, 0.2f, 1.0f, 10.0f, 100.0f, 2.5f, 10.0f, 0.1f, 0.2f};
    float ph[NPHY];
    #pragma unroll
    for (int i = 0; i < NPHY; ++i)
        ph[i] = lb[i] + pg[i * NMULT + m] * (ub[i] - lb[i]);

    const float beta = ph[0], fc = ph[1], k0 = ph[2], k1 = ph[3], k2 = ph[4],
                lp = ph[5], perc = ph[6], uzl = ph[7], ttp = ph[8],
                cfmax = ph[9], cfr = ph[10], cwh = ph[11];
    const float rfc   = 1.0f / fc;
    const float rlpfc = 1.0f / (lp * fc);
    const float cfrcf = cfr * cfmax;

    // Routing weights. gammaln/th^aa cancel in normalization.
    const float aa  = fmaxf(pg[48] * 2.9f, 0.0f) + 0.1f;
    const float th  = fmaxf(pg[49] * 6.5f, 0.0f) + 0.5f;
    const float rth = 1.0f / th;
    const float LOG2E = 1.4426950408889634f;
    float w[LENF];
    float wsum = 0.0f;
    #pragma unroll
    for (int k = 0; k < LENF; ++k) {
        const float tg = (float)k + 0.5f;
        const float e = (aa - 1.0f) * __builtin_log2f(tg) - tg * rth * LOG2E;
        w[k] = __builtin_amdgcn_exp2f(e);
        wsum += w[k];
    }
    const float rw = 1.0f / wsum;
    #pragma unroll
    for (int k = 0; k < LENF; ++k) w[k] *= rw;

    // States
    float snowpack = 0.001f, meltwater = 0.001f, sm = 0.001f, suz = 0.001f, slz = 0.001f;

    // Conv scatter accumulators (all indices compile-time via full unroll)
    float acc[LENF];
    #pragma unroll
    for (int k = 0; k < LENF; ++k) acc[k] = 0.0f;

    const bool writer = (m == 0);
    const float* xg = xphy + 3 * (size_t)g;

    // 2010 = 134*15 padded steps; clamp loads, gate stores.
    for (int t0 = 0; t0 < 2010; t0 += LENF) {
        #pragma unroll
        for (int j = 0; j < LENF; ++j) {
            const int t  = t0 + j;
            const int tl = (t < TT) ? t : (TT - 1);
            const float* xp = xg + (size_t)tl * (3 * NG);
            const float Pt   = xp[0];
            const float Tm   = xp[1];
            const float PETt = xp[2];

            // off-chain precompute
            const float dT      = Tm - ttp;
            const float meltcap = fmaxf(cfmax * dT, 0.0f);
            const float refcap  = fmaxf(-cfrcf * dT, 0.0f);
            const float rain    = (Tm >= ttp) ? Pt : 0.0f;
            const float snow    = Pt - rain;
            // soil wetness depends only on sm_{t-1} -> overlaps snow chain
            const float sw = fminf(__builtin_amdgcn_exp2f(beta * __builtin_amdgcn_logf(sm * rfc)), 1.0f);

            // snow chain
            snowpack += snow;
            const float melt = fminf(meltcap, snowpack);
            meltwater += melt;
            snowpack  -= melt;
            const float refreeze = fminf(refcap, meltwater);
            snowpack  += refreeze;
            meltwater -= refreeze;
            const float tosoil = fmaxf(meltwater - cwh * snowpack, 0.0f);
            meltwater -= tosoil;

            // soil chain
            const float rt       = rain + tosoil;
            const float recharge = rt * sw;
            sm = sm + rt - recharge;
            const float excess = fmaxf(sm - fc, 0.0f);
            sm -= excess;
            const float evap  = fminf(sm * rlpfc, 1.0f);
            const float etact = fminf(sm, PETt * evap);
            sm = fmaxf(sm - etact, 1e-5f);

            // response chain
            suz = suz + recharge + excess;
            const float prc = fminf(suz, perc);
            suz -= prc;
            const float q0 = k0 * fmaxf(suz - uzl, 0.0f);
            suz -= q0;
            const float q1 = k1 * suz;
            suz -= q1;
            slz += prc;
            const float q2 = k2 * slz;
            slz -= q2;
            float q = q0 + q1 + q2;

            // mean over the 4 multipliers (quad-local)
            q += __shfl_xor(q, 1);
            q += __shfl_xor(q, 2);
            q *= 0.25f;

            // fused 15-tap causal convolution, scatter form; head == j
            const float o = acc[j] + w[0] * q;
            acc[j] = 0.0f;
            #pragma unroll
            for (int k = 1; k < LENF; ++k) {
                int idx = j + k;
                if (idx >= LENF) idx -= LENF;
                acc[idx] += w[k] * q;
            }

            if (writer && t >= WARM && t < TT)
                out[(size_t)(t - WARM) * NG + g] = o;
        }
    }
}

extern "C" void kernel_launch(void* const* d_in, const int* in_sizes, int n_in,
                              void* d_out, int out_size, void* d_ws, size_t ws_size,
                              hipStream_t stream) {
    const float* xphy = (const float*)d_in[0];   // [2000, 4000, 3]
    const float* prm  = (const float*)d_in[1];   // [1, 4000, 50]
    float* out = (float*)d_out;                  // [1635, 4000, 1]

    const int threads = NG * NMULT;              // 16000
    hbv_route_kernel<<<(threads + 63) / 64, 64, 0, stream>>>(xphy, prm, out);
}

// Round 3
// 424.179 us; speedup vs baseline: 1.9186x; 1.9186x over previous
//
#include <hip/hip_runtime.h>

#define TT   2000
#define NG   4000
#define WARM 365
#define LENF 15
#define NPHY 12
#define NMULT 4

// One thread per (g, m) chain: 16000 threads, lanes interleaved so the 4
// multipliers of one grid cell occupy one quad (shfl_xor 1,2 = mean over m).
// Time is processed in 15-step blocks with double-buffered register prefetch:
// loads for block k+1 are issued before computing block k, hiding ~900cyc HBM
// latency under ~1500cyc of chain compute.
__global__ __launch_bounds__(64, 1) void hbv_route_kernel(
    const float* __restrict__ xphy,   // [T, G, 3] (p, t, pet)
    const float* __restrict__ prm,    // [1, G, 50]
    float* __restrict__ out)          // [T-WARM, G]
{
    const int tid = blockIdx.x * 64 + threadIdx.x;
    const int g = tid >> 2;
    const int m = tid & 3;
    if (g >= NG) return;

    const float* pg = prm + (size_t)g * (NPHY * NMULT + 2);

    const float lb[NPHY] = {1.0f, 50.0f, 0.05f, 0.01f, 0.001f, 0.2f, 0.0f, 0.0f, -2.5f, 0.5f, 0.0f, 0.0f};
    const float ub[NPHY] = {6.0f, 1000.0f, 0.9f, 0.5f, 0.2f, 1.0f, 10.0f, 100.0f, 2.5f, 10.0f, 0.1f, 0.2f};
    float ph[NPHY];
    #pragma unroll
    for (int i = 0; i < NPHY; ++i)
        ph[i] = lb[i] + pg[i * NMULT + m] * (ub[i] - lb[i]);

    const float beta = ph[0], fc = ph[1], k0 = ph[2], k1 = ph[3], k2 = ph[4],
                lp = ph[5], perc = ph[6], uzl = ph[7], ttp = ph[8],
                cfmax = ph[9], cfr = ph[10], cwh = ph[11];
    const float rfc   = 1.0f / fc;
    const float rlpfc = 1.0f / (lp * fc);
    const float cfrcf = cfr * cfmax;

    // Routing weights. gammaln/th^aa cancel in normalization.
    const float aa  = fmaxf(pg[48] * 2.9f, 0.0f) + 0.1f;
    const float th  = fmaxf(pg[49] * 6.5f, 0.0f) + 0.5f;
    const float rth = 1.0f / th;
    const float LOG2E = 1.4426950408889634f;
    float w[LENF];
    float wsum = 0.0f;
    #pragma unroll
    for (int k = 0; k < LENF; ++k) {
        const float tg = (float)k + 0.5f;
        const float e = (aa - 1.0f) * __builtin_log2f(tg) - tg * rth * LOG2E;
        w[k] = __builtin_amdgcn_exp2f(e);
        wsum += w[k];
    }
    const float rw = 1.0f / wsum;
    #pragma unroll
    for (int k = 0; k < LENF; ++k) w[k] *= rw;

    // States
    float snowpack = 0.001f, meltwater = 0.001f, sm = 0.001f, suz = 0.001f, slz = 0.001f;

    // Conv scatter accumulators (all indices compile-time via full unroll)
    float acc[LENF];
    #pragma unroll
    for (int k = 0; k < LENF; ++k) acc[k] = 0.0f;

    const bool writer = (m == 0);
    const float* xg = xphy + 3 * (size_t)g;

    // Ping-pong register prefetch buffers (compile-time indexed only).
    float pA[LENF], tA[LENF], eA[LENF];
    float pB[LENF], tB[LENF], eB[LENF];

    auto load_blk = [&](int t0, float (&bp)[LENF], float (&bt)[LENF], float (&be)[LENF]) {
        #pragma unroll
        for (int j = 0; j < LENF; ++j) {
            const int t  = t0 + j;
            const int tl = (t < TT) ? t : (TT - 1);
            const float* xp = xg + (size_t)tl * (3 * NG);
            bp[j] = xp[0];
            bt[j] = xp[1];
            be[j] = xp[2];
        }
    };

    auto comp_blk = [&](int t0, const float (&bp)[LENF], const float (&bt)[LENF], const float (&be)[LENF]) {
        #pragma unroll
        for (int j = 0; j < LENF; ++j) {
            const int t = t0 + j;
            const float Pt   = bp[j];
            const float Tm   = bt[j];
            const float PETt = be[j];

            // off-chain precompute
            const float dT      = Tm - ttp;
            const float meltcap = fmaxf(cfmax * dT, 0.0f);
            const float refcap  = fmaxf(-cfrcf * dT, 0.0f);
            const float rain    = (Tm >= ttp) ? Pt : 0.0f;
            const float snow    = Pt - rain;
            // soil wetness depends only on sm_{t-1} -> overlaps snow chain
            const float sw = fminf(__builtin_amdgcn_exp2f(beta * __builtin_amdgcn_logf(sm * rfc)), 1.0f);

            // snow chain
            snowpack += snow;
            const float melt = fminf(meltcap, snowpack);
            meltwater += melt;
            snowpack  -= melt;
            const float refreeze = fminf(refcap, meltwater);
            snowpack  += refreeze;
            meltwater -= refreeze;
            const float tosoil = fmaxf(meltwater - cwh * snowpack, 0.0f);
            meltwater -= tosoil;

            // soil chain
            const float rt       = rain + tosoil;
            const float recharge = rt * sw;
            sm = sm + rt - recharge;
            const float excess = fmaxf(sm - fc, 0.0f);
            sm -= excess;
            const float evap  = fminf(sm * rlpfc, 1.0f);
            const float etact = fminf(sm, PETt * evap);
            sm = fmaxf(sm - etact, 1e-5f);

            // response chain
            suz = suz + recharge + excess;
            const float prc = fminf(suz, perc);
            suz -= prc;
            const float q0 = k0 * fmaxf(suz - uzl, 0.0f);
            suz -= q0;
            const float q1 = k1 * suz;
            suz -= q1;
            slz += prc;
            const float q2 = k2 * slz;
            slz -= q2;
            float q = q0 + q1 + q2;

            // mean over the 4 multipliers (quad-local)
            q += __shfl_xor(q, 1);
            q += __shfl_xor(q, 2);
            q *= 0.25f;

            // fused 15-tap causal convolution, scatter form; head == j
            const float o = acc[j] + w[0] * q;
            acc[j] = 0.0f;
            #pragma unroll
            for (int k = 1; k < LENF; ++k) {
                int idx = j + k;
                if (idx >= LENF) idx -= LENF;
                acc[idx] += w[k] * q;
            }

            if (writer && t >= WARM && t < TT)
                out[(size_t)(t - WARM) * NG + g] = o;
        }
    };

    // 2010 = 67*30 padded steps; clamp loads, gate stores.
    load_blk(0, pA, tA, eA);
    for (int t0 = 0; t0 < 2010; t0 += 2 * LENF) {
        load_blk(t0 + LENF, pB, tB, eB);       // prefetch block k+1
        comp_blk(t0, pA, tA, eA);              // compute block k (hides latency)
        load_blk(t0 + 2 * LENF, pA, tA, eA);   // prefetch block k+2 (clamped at end)
        comp_blk(t0 + LENF, pB, tB, eB);       // compute block k+1
    }
}

extern "C" void kernel_launch(void* const* d_in, const int* in_sizes, int n_in,
                              void* d_out, int out_size, void* d_ws, size_t ws_size,
                              hipStream_t stream) {
    const float* xphy = (const float*)d_in[0];   // [2000, 4000, 3]
    const float* prm  = (const float*)d_in[1];   // [1, 4000, 50]
    float* out = (float*)d_out;                  // [1635, 4000, 1]

    const int threads = NG * NMULT;              // 16000
    hbv_route_kernel<<<(threads + 63) / 64, 64, 0, stream>>>(xphy, prm, out);
}